// Round 10
// baseline (1184.676 us; speedup 1.0000x reference)
//
#include <hip/hip_runtime.h>

typedef __attribute__((ext_vector_type(8))) short bfrag;          // 8 bf16 (4 VGPRs)
typedef __attribute__((ext_vector_type(8))) unsigned short us8;
typedef __attribute__((ext_vector_type(16))) float f16v;          // 32x32 MFMA acc

__device__ __forceinline__ unsigned short f2bf(float f) {
  union { float f; unsigned u; } v; v.f = f;
  unsigned u = v.u;
  return (unsigned short)((u + 0x7fffu + ((u >> 16) & 1u)) >> 16);  // RNE
}
__device__ __forceinline__ unsigned pkbf(float a, float b) {
  return (unsigned)f2bf(a) | ((unsigned)f2bf(b) << 16);
}
__device__ __forceinline__ float wred(float v) {
#pragma unroll
  for (int m = 32; m >= 1; m >>= 1) v += __shfl_xor(v, m, 64);
  return v;
}
// async global->LDS DMA, 16B per lane (global source may be per-lane scattered;
// LDS dest is wave-uniform base + lane*16).
__device__ __forceinline__ void dma16(const void* g, void* l) {
  __builtin_amdgcn_global_load_lds(
      (const __attribute__((address_space(1))) void*)g,
      (__attribute__((address_space(3))) void*)l, 16, 0, 0);
}

// ---------------------------------------------------------------------------
// Fused prep kernel (r8 form). Flattened 1-D grid, block 256:
//   [0, 2048)      : point_emb fp32->bf16 cast (peT)
//   [2048, 3072)   : img transpose + fused pos-add (LDS-tiled)
//   [3072, 3264)   : Wq/Wk/Wv 256x256 transposes (12 z-slices)
//   [3264, 3328)   : Wo 1024x256 transpose
// ---------------------------------------------------------------------------
__device__ __forceinline__ void transp64(
    const float* __restrict__ inz, unsigned short* __restrict__ oz,
    int R, int Cc, int i0, int j0, int tid)
{
  int l = tid & 63, ty = tid >> 6;
  int i = i0 + l;
#pragma unroll
  for (int itr = 0; itr < 2; ++itr) {
    int j = j0 + ty * 16 + itr * 8;
    const float* p = inz + (long)i * Cc + j;
    float4 v0 = *(const float4*)(p);
    float4 v1 = *(const float4*)(p + 4);
    float vv[8] = {v0.x, v0.y, v0.z, v0.w, v1.x, v1.y, v1.z, v1.w};
#pragma unroll
    for (int s = 0; s < 8; ++s) oz[(long)(j + s) * R + i] = f2bf(vv[s]);
  }
}

__global__ __launch_bounds__(256) void prep_kernel(
    const float* __restrict__ point_emb, short* __restrict__ peT,
    const float* __restrict__ img_emb, const float* __restrict__ pos,
    short* __restrict__ imgT, short* __restrict__ imgPosT,
    const float* __restrict__ Wq, const float* __restrict__ Wk,
    const float* __restrict__ Wv, short* __restrict__ WqT,
    const float* __restrict__ Wo, short* __restrict__ WoT)
{
  __shared__ float tile[64][65];   // 16.6KB, img-transpose path only
  int b = blockIdx.x;
  int tid = threadIdx.x;

  if (b < 2048) {
    // ---- point_emb cast: 8 elems/thread ----
    long i = ((long)b * 256 + tid) * 8;
    float4 v0 = *(const float4*)(point_emb + i);
    float4 v1 = *(const float4*)(point_emb + i + 4);
    uint4 st;
    st.x = pkbf(v0.x, v0.y);
    st.y = pkbf(v0.z, v0.w);
    st.z = pkbf(v1.x, v1.y);
    st.w = pkbf(v1.z, v1.w);
    *(uint4*)((unsigned short*)peT + i) = st;
  } else if (b < 3072) {
    // ---- img transpose + fused pos-add, LDS-tiled ----
    int bb = b - 2048;                 // x=bb&63 (token tile), y=(bb>>6)&3 (ch tile), z=bb>>8
    int x = bb & 63, y = (bb >> 6) & 3, z = bb >> 8;
    long zofs = (long)z * (256L * 4096L);
    const float* inz = img_emb + zofs;
    int i0 = y * 64, j0 = x * 64;      // i: channel, j: token
    int r0 = (tid >> 6) * 16, c = tid & 63;
#pragma unroll
    for (int rr = 0; rr < 16; ++rr) {
      tile[c][r0 + rr] = inz[(long)(i0 + r0 + rr) * 4096 + j0 + c];
    }
    __syncthreads();
    unsigned short* o1 = (unsigned short*)imgT + zofs;
    unsigned short* o2 = (unsigned short*)imgPosT + zofs;
#pragma unroll
    for (int rr = 0; rr < 16; ++rr) {
      int tt = r0 + rr;
      float v = tile[tt][c];
      long o = (long)(j0 + tt) * 256 + i0 + c;
      o1[o] = f2bf(v);
      o2[o] = f2bf(v + pos[o]);
    }
  } else if (b < 3264) {
    // ---- Wq/Wk/Wv transposes: 12 z-slices of 256x256 ----
    int bb = b - 3072;
    int x = bb & 3, y = (bb >> 2) & 3, z = bb >> 4;   // z in [0,12)
    const float* inz = (z < 4 ? Wq : (z < 8 ? Wk : Wv)) + (long)(z & 3) * 65536;
    unsigned short* oz = (unsigned short*)WqT + (long)z * 65536;
    transp64(inz, oz, 256, 256, x * 64, y * 64, tid);
  } else {
    // ---- Wo transpose: 1024x256 ----
    int bb = b - 3264;
    int x = bb & 15, y = bb >> 4;
    transp64(Wo, (unsigned short*)WoT, 1024, 256, x * 64, y * 64, tid);
  }
}

// ---------------------------------------------------------------------------
// Merged Q+K GEMM: one 4096-block launch; id<2048 computes Q, else K.
// ---------------------------------------------------------------------------
__global__ __launch_bounds__(256) void gemm_qk(
    const short* __restrict__ Aq, const short* __restrict__ Btq,
    const float* __restrict__ biasq, short* __restrict__ Cq,
    const short* __restrict__ Ak, const short* __restrict__ Btk,
    const float* __restrict__ biask, short* __restrict__ Ck,
    float qscale)
{
  int idg = blockIdx.x;
  int sel = idg >> 11;               // 0 = Q, 1 = K
  int id = idg & 2047;
  const short* A  = sel ? Ak : Aq;
  const short* Bt = sel ? Btk : Btq;
  const float* bias = sel ? biask : biasq;
  short* Co = sel ? Ck : Cq;
  float scale = sel ? 1.0f : qscale;

  int y = id & 3, h = (id >> 2) & 3;
  int g = id >> 4;
  int xt = g & 31, bsel = g >> 5;
  int z = bsel * 4 + h;

  const short* Az = A + (long)bsel * 1048576;
  const short* Btz = Bt + (long)h * 65536;
  const float* biasz = bias + (long)h * 256;
  short* Cz = Co + (long)z * 1048576;

  int tid = threadIdx.x;
  int w = tid >> 6, lane = tid & 63;
  int half = lane >> 5, ln = lane & 31;
  int wm = w & 1, wn = w >> 1;
  int row0 = xt * 128 + wm * 64;
  int col0 = y * 64 + wn * 32;

  f16v acc0, acc1;
#pragma unroll
  for (int i = 0; i < 16; ++i) { acc0[i] = 0.f; acc1[i] = 0.f; }

  const short* ap0 = Az + (long)(row0 + ln) * 256 + half * 8;
  const short* ap1 = Az + (long)(row0 + 32 + ln) * 256 + half * 8;
  const short* bp  = Btz + (long)(col0 + ln) * 256 + half * 8;

#pragma unroll
  for (int kt = 0; kt < 16; ++kt) {
    bfrag a0 = *(const bfrag*)(ap0 + kt * 16);
    bfrag a1 = *(const bfrag*)(ap1 + kt * 16);
    bfrag bbv = *(const bfrag*)(bp + kt * 16);
    acc0 = __builtin_amdgcn_mfma_f32_32x32x16_bf16(a0, bbv, acc0, 0, 0, 0);
    acc1 = __builtin_amdgcn_mfma_f32_32x32x16_bf16(a1, bbv, acc1, 0, 0, 0);
  }

  int col = col0 + ln;
  float bv = biasz[col];
#pragma unroll
  for (int t = 0; t < 2; ++t) {
    int rbase = row0 + t * 32;
#pragma unroll
    for (int r = 0; r < 16; ++r) {
      float av = t ? acc1[r] : acc0[r];
      int rr = rbase + (r & 3) + 8 * (r >> 2) + 4 * half;
      ((unsigned short*)Cz)[(long)rr * 256 + col] = f2bf((av + bv) * scale);
    }
  }
}

// ---------------------------------------------------------------------------
// V GEMM (transC): V^T = ((img+pos) @ WvT + bv)^T. Separate launch (its
// output region overlaps peT/imgT — stream order is load-bearing).
// ---------------------------------------------------------------------------
__global__ __launch_bounds__(256) void gemm_v(
    const short* __restrict__ A, const short* __restrict__ Bt,
    const float* __restrict__ bias, short* __restrict__ Co)
{
  int id = blockIdx.x;
  int y = id & 3, h = (id >> 2) & 3;
  int g = id >> 4;
  int xt = g & 31, bsel = g >> 5;
  int z = bsel * 4 + h;

  const short* Az = A + (long)bsel * 1048576;
  const short* Btz = Bt + (long)h * 65536;
  const float* biasz = bias + (long)h * 256;
  short* Cz = Co + (long)z * 1048576;

  int tid = threadIdx.x;
  int w = tid >> 6, lane = tid & 63;
  int half = lane >> 5, ln = lane & 31;
  int wm = w & 1, wn = w >> 1;
  int row0 = xt * 128 + wm * 64;
  int col0 = y * 64 + wn * 32;

  f16v acc0, acc1;
#pragma unroll
  for (int i = 0; i < 16; ++i) { acc0[i] = 0.f; acc1[i] = 0.f; }

  const short* ap0 = Az + (long)(row0 + ln) * 256 + half * 8;
  const short* ap1 = Az + (long)(row0 + 32 + ln) * 256 + half * 8;
  const short* bp  = Btz + (long)(col0 + ln) * 256 + half * 8;

#pragma unroll
  for (int kt = 0; kt < 16; ++kt) {
    bfrag a0 = *(const bfrag*)(ap0 + kt * 16);
    bfrag a1 = *(const bfrag*)(ap1 + kt * 16);
    bfrag bbv = *(const bfrag*)(bp + kt * 16);
    acc0 = __builtin_amdgcn_mfma_f32_32x32x16_bf16(a0, bbv, acc0, 0, 0, 0);
    acc1 = __builtin_amdgcn_mfma_f32_32x32x16_bf16(a1, bbv, acc1, 0, 0, 0);
  }

  int col = col0 + ln;
  float bv = biasz[col];
#pragma unroll
  for (int t = 0; t < 2; ++t) {
    int rbase = row0 + t * 32;
#pragma unroll
    for (int g2 = 0; g2 < 4; ++g2) {
      float v0 = (t ? acc1[4*g2+0] : acc0[4*g2+0]) + bv;
      float v1 = (t ? acc1[4*g2+1] : acc0[4*g2+1]) + bv;
      float v2 = (t ? acc1[4*g2+2] : acc0[4*g2+2]) + bv;
      float v3 = (t ? acc1[4*g2+3] : acc0[4*g2+3]) + bv;
      uint2 st;
      st.x = pkbf(v0, v1);
      st.y = pkbf(v2, v3);
      *(uint2*)&((unsigned short*)Cz)[(long)col * 4096 + rbase + 8 * g2 + 4 * half] = st;
    }
  }
}

// ---------------------------------------------------------------------------
// Output projection (compile-time shape M=16384 N=256 K=1024), r8 form.
// ---------------------------------------------------------------------------
__global__ __launch_bounds__(256) void gemm_out(
    const short* __restrict__ A, const short* __restrict__ Bt,
    const float* __restrict__ bias, float* __restrict__ Co,
    const float* __restrict__ resid)
{
  int id = blockIdx.x;
  int xt = id >> 2, y = id & 3;

  int tid = threadIdx.x;
  int w = tid >> 6, lane = tid & 63;
  int half = lane >> 5, ln = lane & 31;
  int wm = w & 1, wn = w >> 1;
  int row0 = xt * 128 + wm * 64;
  int col0 = y * 64 + wn * 32;

  f16v acc0, acc1;
#pragma unroll
  for (int i = 0; i < 16; ++i) { acc0[i] = 0.f; acc1[i] = 0.f; }

  int r0 = row0 + ln, r1 = row0 + 32 + ln;
  long a0base = (long)(r0 >> 12) * 4194304 + (long)(r0 & 4095) * 256 + half * 8;
  long a1base = (long)(r1 >> 12) * 4194304 + (long)(r1 & 4095) * 256 + half * 8;
  const short* bp = Bt + (long)(col0 + ln) * 1024 + half * 8;

  for (int kh = 0; kh < 4; ++kh) {          // head-major K blocks
    const short* a0p = A + a0base + (long)kh * 1048576;
    const short* a1p = A + a1base + (long)kh * 1048576;
    const short* bkp = bp + kh * 256;
#pragma unroll
    for (int kt = 0; kt < 16; ++kt) {
      bfrag a0 = *(const bfrag*)(a0p + kt * 16);
      bfrag a1 = *(const bfrag*)(a1p + kt * 16);
      bfrag bbv = *(const bfrag*)(bkp + kt * 16);
      acc0 = __builtin_amdgcn_mfma_f32_32x32x16_bf16(a0, bbv, acc0, 0, 0, 0);
      acc1 = __builtin_amdgcn_mfma_f32_32x32x16_bf16(a1, bbv, acc1, 0, 0, 0);
    }
  }

  int col = col0 + ln;
  float bv = bias[col];
#pragma unroll
  for (int t = 0; t < 2; ++t) {
    int rbase = row0 + t * 32;
#pragma unroll
    for (int r = 0; r < 16; ++r) {
      float av = t ? acc1[r] : acc0[r];
      int rr = rbase + (r & 3) + 8 * (r >> 2) + 4 * half;
      Co[(long)rr * 256 + col] = av + bv + resid[(long)rr * 256 + col];
    }
  }
}

// ---------------------------------------------------------------------------
// Flash attention — ROUND 10: K direct from global (L1/L2), off the LDS pipe.
// r9 diagnosis: 320KB/iter of ds_read at ~85B/cyc = ~80% of the iteration;
// LDS-read-bound. The swizzled K LDS read resolves to plain row-major
// (token=t0+ln, d=kt*16+half*8), so K-frags are now loaded directly from Kb:
// 16KB tile fits L1; reads ride the idle VMEM pipe and overlap V+Q ds_reads.
// K-DMA and K LDS space removed: LDS = 2x16KB V dbuf + 64KB Q = 96KB;
// LDS reads 320->192 KB/iter. Pipeline parity/structure unchanged.
// Closed: setprio (r1), 4-wave 2-block/CU (r3/r5), launch-fusion (r6-null).
// ---------------------------------------------------------------------------
__global__ __launch_bounds__(512, 2) void attn_kernel(
    const short* __restrict__ Qg, const short* __restrict__ Kg,
    const short* __restrict__ Vtg, short* __restrict__ attc)
{
  __shared__ char smem[98304];  // [0,32K): V dbuf (2x16KB); [32K,96K): Q frags 8..15
  int bx = blockIdx.x;
  int bh = bx & 15, qg = bx >> 4;          // head-major XCD swizzle (load-bearing)
  int tid = threadIdx.x;
  int w = tid >> 6, lane = tid & 63;
  int half = lane >> 5, ln = lane & 31;
  int q0 = qg * 256 + w * 32;

  // Q fragments: kt 0..7 in registers; kt 8..15 in per-wave LDS (write-once,
  // same-wave reads only -> compiler-tracked lgkmcnt, no barrier needed).
  bfrag qf[8];
  int qoff = 32768 + w * 8192 + lane * 16;
  {
    const short* qrow = Qg + ((long)bh * 4096 + q0 + ln) * 256 + half * 8;
#pragma unroll
    for (int kt = 0; kt < 8; ++kt) qf[kt] = *(const bfrag*)(qrow + kt * 16);
#pragma unroll
    for (int kt = 8; kt < 16; ++kt) {
      us8 v = *(const us8*)(qrow + kt * 16);
      *(us8*)(smem + qoff + (kt - 8) * 1024) = v;
    }
  }

  // V LDS read offsets (swizzle unchanged; base now 0 per 16KB buffer)
  int voff[2];
#pragma unroll
  for (int kp = 0; kp < 2; ++kp) {
    int ck = 2 * kp + half;
    voff[kp] = ck * 4096 + ((ln ^ (ck << 1)) * 16);
  }

  // direct-global K: lane ln reads token (t0+ln), elems d = kt*16 + half*8.
  // (algebraically identical to the old swizzled-LDS fragment — verified.)
  const short* kdir = Kg + ((long)bh * 4096 + ln) * 256 + half * 8;

  // V DMA source offsets (inverse swizzle on the global side), as r4-r9.
  int w2 = w * 2;
  int vgl0, vgl1;
  {
    int ck0 = w2 >> 2;
    int e0 = ((w2 & 3) * 64 + lane) ^ (ck0 << 1);
    vgl0 = e0 * 8192 + ck0 * 16;
    int ck1 = (w2 + 1) >> 2;
    int e1 = (((w2 + 1) & 3) * 64 + lane) ^ (ck1 << 1);
    vgl1 = e1 * 8192 + ck1 * 16;
  }
  const char* vgp = (const char*)Vtg + (long)bh * 2097152;  // += 64 per tile

  f16v O[8];
#pragma unroll
  for (int t = 0; t < 8; ++t)
#pragma unroll
    for (int r = 0; r < 16; ++r) O[t][r] = 0.f;

  float l_run = 0.f;
  union { bfrag f; unsigned u[4]; } bb[2];
  f16v SA, SB;                      // two-deep S pipeline (static rotation)

// softmax P-pack from SV: cvt_pk pairs + permlane32_swap lane-halves exchange.
#define PACK_BB(kp, SV)                                                        \
  {                                                                            \
    unsigned q0_, q1_, q2_, q3_;                                               \
    asm("v_cvt_pk_bf16_f32 %0, %1, %2"                                         \
        : "=v"(q0_) : "v"(SV[8*(kp)+0]), "v"(SV[8*(kp)+1]));                   \
    asm("v_cvt_pk_bf16_f32 %0, %1, %2"                                         \
        : "=v"(q1_) : "v"(SV[8*(kp)+2]), "v"(SV[8*(kp)+3]));                   \
    asm("v_cvt_pk_bf16_f32 %0, %1, %2"                                         \
        : "=v"(q2_) : "v"(SV[8*(kp)+4]), "v"(SV[8*(kp)+5]));                   \
    asm("v_cvt_pk_bf16_f32 %0, %1, %2"                                         \
        : "=v"(q3_) : "v"(SV[8*(kp)+6]), "v"(SV[8*(kp)+7]));                   \
    asm("v_permlane32_swap_b32 %0, %1" : "+v"(q0_), "+v"(q2_));                \
    asm("v_permlane32_swap_b32 %0, %1" : "+v"(q1_), "+v"(q3_));                \
    bb[kp].u[0] = q0_;                                                         \
    bb[kp].u[1] = q1_;                                                         \
    bb[kp].u[2] = q2_;                                                         \
    bb[kp].u[3] = q3_;                                                         \
  }

// exp/sum/pack of SV (tile t-1) -> l_run, bb
#define SOFTMAX_BB(SV)                                                         \
  {                                                                            \
    float ss = 0.f;                                                            \
    _Pragma("unroll")                                                          \
    for (int r = 0; r < 16; ++r) { float e = exp2f(SV[r] - 8.f); SV[r] = e; ss += e; } \
    l_run += ss;                                                               \
    PACK_BB(0, SV)                                                             \
    PACK_BB(1, SV)                                                             \
  }

// S-MFMA chain for the current tile, K direct from global; bumps kdir.
#define SCHAIN(SNEW)                                                           \
  {                                                                            \
    _Pragma("unroll")                                                          \
    for (int r = 0; r < 16; ++r) SNEW[r] = 0.f;                                \
    _Pragma("unroll")                                                          \
    for (int kt = 0; kt < 8; ++kt) {                                           \
      bfrag a = *(const bfrag*)(kdir + kt * 16);                               \
      SNEW = __builtin_amdgcn_mfma_f32_32x32x16_bf16(a, qf[kt], SNEW, 0, 0, 0);\
    }                                                                          \
    _Pragma("unroll")                                                          \
    for (int kt = 8; kt < 16; ++kt) {                                          \
      bfrag a = *(const bfrag*)(kdir + kt * 16);                               \
      bfrag qv = *(const bfrag*)(smem + qoff + (kt - 8) * 1024);               \
      SNEW = __builtin_amdgcn_mfma_f32_32x32x16_bf16(a, qv, SNEW, 0, 0, 0);    \
    }                                                                          \
    kdir += 8192;   /* 32 tokens x 256 elems = next tile */                    \
  }

  // iter 0: DMA V_0 -> buf1; S(K_0) -> SB (K direct; no barrier needed yet —
  // SCHAIN touches only own-wave Q LDS).
  dma16(vgp + vgl0, smem + 16384 + w2 * 1024);
  dma16(vgp + vgl1, smem + 16384 + (w2 + 1) * 1024);
  vgp += 64;
  SCHAIN(SB)

// iteration t (BUF = parity): barrier drains V_{t-1} DMA; DMA V_t -> BUF^1;
// S(t) -> SNEW (K direct, VMEM pipe) || softmax(t-1) on SPREV (VALU);
// then O += V_{t-1}(BUF) * bb.
#define ATTN_ITER(BUF, SNEW, SPREV)                                            \
  {                                                                            \
    __syncthreads();                                                           \
    dma16(vgp + vgl0, smem + ((BUF) ^ 1) * 16384 + w2 * 1024);                 \
    dma16(vgp + vgl1, smem + ((BUF) ^ 1) * 16384 + (w2 + 1) * 1024);           \
    vgp += 64;                                                                 \
    SCHAIN(SNEW)                                                               \
    SOFTMAX_BB(SPREV)                                                          \
    _Pragma("unroll")                                                          \
    for (int kt = 0; kt < 16; ++kt) {                                          \
      bfrag va = *(const bfrag*)(smem + voff[kt >> 3] +                        \
                                 ((BUF)*16384 + (kt & 7) * 512));              \
      O[kt & 7] = __builtin_amdgcn_mfma_f32_32x32x16_bf16(va, bb[kt >> 3].f,   \
                                                          O[kt & 7], 0, 0, 0); \
    }                                                                          \
  }

  // t = 1..126 as 63 static-parity pairs, then t = 127.
  for (int tp = 0; tp < 63; ++tp) {
    ATTN_ITER(1, SA, SB)     // odd t: new S in SA, softmax SB
    ATTN_ITER(0, SB, SA)     // even t
  }
  ATTN_ITER(1, SA, SB)       // t = 127: V_127 DMA'd into buf0

  // epilogue: softmax(S_127)=SA, then V-MFMA for tile 127 (buf0)
  __syncthreads();
  SOFTMAX_BB(SA)
#pragma unroll
  for (int kp = 0; kp < 2; ++kp) {
#pragma unroll
    for (int mt = 0; mt < 8; ++mt) {
      bfrag va = *(const bfrag*)(smem + voff[kp] + mt * 512);
      O[mt] = __builtin_amdgcn_mfma_f32_32x32x16_bf16(va, bb[kp].f, O[mt], 0, 0, 0);
    }
  }
#undef ATTN_ITER
#undef SCHAIN
#undef SOFTMAX_BB
#undef PACK_BB

  // attc[bh][q][e] = O^T[e][q]/l.  l = own-half + partner-half.
  l_run += __shfl_xor(l_run, 32);
  float rl = 1.0f / l_run;
  short* orow = attc + ((long)bh * 4096 + q0 + ln) * 256;
#pragma unroll
  for (int mt = 0; mt < 8; ++mt) {
#pragma unroll
    for (int g = 0; g < 4; ++g) {
      uint2 st;
      st.x = pkbf(O[mt][4 * g + 0] * rl, O[mt][4 * g + 1] * rl);
      st.y = pkbf(O[mt][4 * g + 2] * rl, O[mt][4 * g + 3] * rl);
      *(uint2*)(orow + mt * 32 + 8 * g + 4 * half) = st;
    }
  }
}

// ---------------------------------------------------------------------------
// FFN head (all fp32): 16 rows per 256-thr block, 4 rows per wave.
// ---------------------------------------------------------------------------
__global__ __launch_bounds__(256) void ffn_kernel(
    const float* __restrict__ emb,
    const float* __restrict__ W1, const float* __restrict__ b1,
    const float* __restrict__ g1, const float* __restrict__ be1,
    const float* __restrict__ W2, const float* __restrict__ b2,
    const float* __restrict__ g2, const float* __restrict__ be2,
    const float* __restrict__ W3, const float* __restrict__ b3,
    float* __restrict__ act)
{
  __shared__ float xs[4][256][4];   // [wave][k][row]  16KB
  __shared__ float hs[4][128][4];   // [wave][k][row]   8KB
  int w = threadIdx.x >> 6, l = threadIdx.x & 63;
  int row0 = blockIdx.x * 16 + w * 4;
  const float* x = emb + (long)row0 * 256;

  {
    float xv[4][4];
#pragma unroll
    for (int rr = 0; rr < 4; ++rr) {
      float4 t = *(const float4*)(x + rr * 256 + 4 * l);
      xv[0][rr] = t.x; xv[1][rr] = t.y; xv[2][rr] = t.z; xv[3][rr] = t.w;
    }
#pragma unroll
    for (int i = 0; i < 4; ++i) {
      float4 st = make_float4(xv[i][0], xv[i][1], xv[i][2], xv[i][3]);
      *(float4*)&xs[w][4 * l + i][0] = st;
    }
  }

  float a0[4], a1[4];
  {
    float bb0 = b1[2 * l], bb1 = b1[2 * l + 1];
#pragma unroll
    for (int rr = 0; rr < 4; ++rr) { a0[rr] = bb0; a1[rr] = bb1; }
  }
  for (int k = 0; k < 256; ++k) {
    float w0 = W1[k * 128 + 2 * l], w1 = W1[k * 128 + 2 * l + 1];
    float4 xv = *(const float4*)&xs[w][k][0];
    a0[0] += xv.x * w0; a1[0] += xv.x * w1;
    a0[1] += xv.y * w0; a1[1] += xv.y * w1;
    a0[2] += xv.z * w0; a1[2] += xv.z * w1;
    a0[3] += xv.w * w0; a1[3] += xv.w * w1;
  }
  {
    float gg0 = g1[2 * l], gg1 = g1[2 * l + 1];
    float ee0 = be1[2 * l], ee1 = be1[2 * l + 1];
    float n0v[4], n1v[4];
#pragma unroll
    for (int rr = 0; rr < 4; ++rr) {
      float u0 = fmaxf(a0[rr], 0.f), u1 = fmaxf(a1[rr], 0.f);
      float s1 = wred(u0 + u1);
      float s2 = wred(u0 * u0 + u1 * u1);
      float mu = s1 * (1.f / 128.f);
      float var = fmaxf(s2 * (1.f / 128.f) - mu * mu, 0.f);
      float rs = rsqrtf(var + 1e-5f);
      n0v[rr] = (u0 - mu) * rs * gg0 + ee0;
      n1v[rr] = (u1 - mu) * rs * gg1 + ee1;
    }
    *(float4*)&hs[w][2 * l][0]     = make_float4(n0v[0], n0v[1], n0v[2], n0v[3]);
    *(float4*)&hs[w][2 * l + 1][0] = make_float4(n1v[0], n1v[1], n1v[2], n1v[3]);
  }

  float c0[4];
  {
    float bb2 = b2[l];
#pragma unroll
    for (int rr = 0; rr < 4; ++rr) c0[rr] = bb2;
  }
  for (int k = 0; k < 128; ++k) {
    float w2 = W2[k * 64 + l];
    float4 hv = *(const float4*)&hs[w][k][0];
    c0[0] += hv.x * w2;
    c0[1] += hv.y * w2;
    c0[2] += hv.z * w2;
    c0[3] += hv.w * w2;
  }
  {
    float gg2 = g2[l], ee2 = be2[l], w3 = W3[l], bb3 = b3[0];
#pragma unroll
    for (int rr = 0; rr < 4; ++rr) {
      float u = fmaxf(c0[rr], 0.f);
      float t1 = wred(u);
      float t2 = wred(u * u);
      float mu2 = t1 * (1.f / 64.f);
      float var2 = fmaxf(t2 * (1.f / 64.f) - mu2 * mu2, 0.f);
      float rs2 = rsqrtf(var2 + 1e-5f);
      float n2 = (u - mu2) * rs2 * gg2 + ee2;
      float tt = wred(n2 * w3);
      if (l == 0) {
        float r = tt + bb3;
        act[row0 + rr] = 1.f / (1.f + __expf(-r));
      }
    }
  }
}

// ---------------------------------------------------------------------------
extern "C" void kernel_launch(void* const* d_in, const int* in_sizes, int n_in,
                              void* d_out, int out_size, void* d_ws, size_t ws_size,
                              hipStream_t stream)
{
  const float* img_emb   = (const float*)d_in[0];
  const float* point_emb = (const float*)d_in[1];
  const float* Wq = (const float*)d_in[2];
  const float* bq = (const float*)d_in[3];
  const float* Wk = (const float*)d_in[4];
  const float* bk = (const float*)d_in[5];
  const float* Wv = (const float*)d_in[6];
  const float* bv = (const float*)d_in[7];
  const float* Wo = (const float*)d_in[8];
  const float* bo = (const float*)d_in[9];
  const float* pos = (const float*)d_in[10];
  const float* W1 = (const float*)d_in[11];
  const float* b1 = (const float*)d_in[12];
  const float* g1 = (const float*)d_in[13];
  const float* be1 = (const float*)d_in[14];
  const float* W2 = (const float*)d_in[15];
  const float* b2 = (const float*)d_in[16];
  const float* g2 = (const float*)d_in[17];
  const float* be2 = (const float*)d_in[18];
  const float* W3 = (const float*)d_in[19];
  const float* b3 = (const float*)d_in[20];

  // ws layout (111.1 MB), all internal tensors bf16.
  // peT/imgT live INSIDE the VtB region: both are dead before gemm_v (the
  // only writer of VtB) runs — stream order guarantees safety.
  char* ws = (char*)d_ws;
  short* Qb      = (short*)(ws + 0);            // 33.55 MB [BH][4096][256]; attn out in-place
  short* Kb      = (short*)(ws + 33554432);     // 33.55 MB [BH][4096][256]
  short* VtB     = (short*)(ws + 67108864);     // 33.55 MB [BH][256][4096]
  short* peT     = (short*)(ws + 67108864);     //  8.39 MB (dead after QK launch)
  short* imgT    = (short*)(ws + 75497472);     //  8.39 MB (dead after QK launch)
  short* imgPosT = (short*)(ws + 100663296);    //  8.39 MB
  short* WoT     = (short*)(ws + 109051904);    //  0.52 MB [256][1024]
  short* WqT     = (short*)(ws + 109576192);    //  0.13 MB [H][256][256]  (WkT,WvT follow)
  short* WkT     = (short*)(ws + 110100480);
  short* WvT     = (short*)(ws + 110624768);
  (void)WkT; (void)WvT;

  float* act_out = (float*)d_out;            // [B*N]
  float* emb_out = (float*)d_out + 16384;    // [B*N][256]

  const float qscale = 0.0901684400555602f;  // log2(e)/sqrt(256)

  // fused prep: all weight transposes + img transpose/pos-add + point_emb cast
  prep_kernel<<<3328, 256, 0, stream>>>(point_emb, peT, img_emb, pos,
                                        imgT, imgPosT, Wq, Wk, Wv, WqT, Wo, WoT);

  // Q and K GEMMs merged into one launch (no aliasing between their buffers)
  gemm_qk<<<4096, 256, 0, stream>>>(peT, WqT, bq, Qb,
                                    imgT, WqT + 262144, bk, Kb, qscale);
  // V^T = ((img + pos) @ WvT + bv)^T   (writes VtB over peT/imgT — after QK)
  gemm_v<<<2048, 256, 0, stream>>>(imgPosT, WqT + 524288, bv, VtB);

  // attention: reads Qb/Kb/VtB, writes att in-place over Qb ([BH][N][256])
  attn_kernel<<<256, 512, 0, stream>>>(Qb, Kb, VtB, Qb);

  // emb = att @ Wo + bo + point_emb  (fp32 out)
  gemm_out<<<512, 256, 0, stream>>>(Qb, WoT, bo, emb_out, point_emb);

  // FFN head -> act (fp32)
  ffn_kernel<<<1024, 256, 0, stream>>>(emb_out, W1, b1, g1, be1, W2, b2, g2, be2,
                                       W3, b3, act_out);
}

// Round 11
// 609.925 us; speedup vs baseline: 1.9423x; 1.9423x over previous
//
#include <hip/hip_runtime.h>

typedef __attribute__((ext_vector_type(8))) short bfrag;          // 8 bf16 (4 VGPRs)
typedef __attribute__((ext_vector_type(8))) unsigned short us8;
typedef __attribute__((ext_vector_type(16))) float f16v;          // 32x32 MFMA acc

__device__ __forceinline__ unsigned short f2bf(float f) {
  union { float f; unsigned u; } v; v.f = f;
  unsigned u = v.u;
  return (unsigned short)((u + 0x7fffu + ((u >> 16) & 1u)) >> 16);  // RNE
}
__device__ __forceinline__ unsigned pkbf(float a, float b) {
  return (unsigned)f2bf(a) | ((unsigned)f2bf(b) << 16);
}
__device__ __forceinline__ float wred(float v) {
#pragma unroll
  for (int m = 32; m >= 1; m >>= 1) v += __shfl_xor(v, m, 64);
  return v;
}
// async global->LDS DMA, 16B per lane (global source may be per-lane scattered;
// LDS dest is wave-uniform base + lane*16).
__device__ __forceinline__ void dma16(const void* g, void* l) {
  __builtin_amdgcn_global_load_lds(
      (const __attribute__((address_space(1))) void*)g,
      (__attribute__((address_space(3))) void*)l, 16, 0, 0);
}

// ---------------------------------------------------------------------------
// Fused prep kernel. Flattened 1-D grid, block 256:
//   [0, 2048)      : point_emb fp32->bf16 cast (peT)
//   [2048, 3072)   : img transpose + fused pos-add (LDS-tiled)
//   [3072, 3264)   : Wq/Wk/Wv 256x256 transposes (12 z-slices)
//   [3264, 3328)   : Wo 1024x256 transpose
// ---------------------------------------------------------------------------
__device__ __forceinline__ void transp64(
    const float* __restrict__ inz, unsigned short* __restrict__ oz,
    int R, int Cc, int i0, int j0, int tid)
{
  int l = tid & 63, ty = tid >> 6;
  int i = i0 + l;
#pragma unroll
  for (int itr = 0; itr < 2; ++itr) {
    int j = j0 + ty * 16 + itr * 8;
    const float* p = inz + (long)i * Cc + j;
    float4 v0 = *(const float4*)(p);
    float4 v1 = *(const float4*)(p + 4);
    float vv[8] = {v0.x, v0.y, v0.z, v0.w, v1.x, v1.y, v1.z, v1.w};
#pragma unroll
    for (int s = 0; s < 8; ++s) oz[(long)(j + s) * R + i] = f2bf(vv[s]);
  }
}

__global__ __launch_bounds__(256) void prep_kernel(
    const float* __restrict__ point_emb, short* __restrict__ peT,
    const float* __restrict__ img_emb, const float* __restrict__ pos,
    short* __restrict__ imgT, short* __restrict__ imgPosT,
    const float* __restrict__ Wq, const float* __restrict__ Wk,
    const float* __restrict__ Wv, short* __restrict__ WqT,
    const float* __restrict__ Wo, short* __restrict__ WoT)
{
  __shared__ float tile[64][65];   // 16.6KB, img-transpose path only
  int b = blockIdx.x;
  int tid = threadIdx.x;

  if (b < 2048) {
    // ---- point_emb cast: 8 elems/thread ----
    long i = ((long)b * 256 + tid) * 8;
    float4 v0 = *(const float4*)(point_emb + i);
    float4 v1 = *(const float4*)(point_emb + i + 4);
    uint4 st;
    st.x = pkbf(v0.x, v0.y);
    st.y = pkbf(v0.z, v0.w);
    st.z = pkbf(v1.x, v1.y);
    st.w = pkbf(v1.z, v1.w);
    *(uint4*)((unsigned short*)peT + i) = st;
  } else if (b < 3072) {
    // ---- img transpose + fused pos-add, LDS-tiled ----
    int bb = b - 2048;                 // x=bb&63 (token tile), y=(bb>>6)&3 (ch tile), z=bb>>8
    int x = bb & 63, y = (bb >> 6) & 3, z = bb >> 8;
    long zofs = (long)z * (256L * 4096L);
    const float* inz = img_emb + zofs;
    int i0 = y * 64, j0 = x * 64;      // i: channel, j: token
    int r0 = (tid >> 6) * 16, c = tid & 63;
#pragma unroll
    for (int rr = 0; rr < 16; ++rr) {
      tile[c][r0 + rr] = inz[(long)(i0 + r0 + rr) * 4096 + j0 + c];
    }
    __syncthreads();
    unsigned short* o1 = (unsigned short*)imgT + zofs;
    unsigned short* o2 = (unsigned short*)imgPosT + zofs;
#pragma unroll
    for (int rr = 0; rr < 16; ++rr) {
      int tt = r0 + rr;
      float v = tile[tt][c];
      long o = (long)(j0 + tt) * 256 + i0 + c;
      o1[o] = f2bf(v);
      o2[o] = f2bf(v + pos[o]);
    }
  } else if (b < 3264) {
    // ---- Wq/Wk/Wv transposes: 12 z-slices of 256x256 ----
    int bb = b - 3072;
    int x = bb & 3, y = (bb >> 2) & 3, z = bb >> 4;   // z in [0,12)
    const float* inz = (z < 4 ? Wq : (z < 8 ? Wk : Wv)) + (long)(z & 3) * 65536;
    unsigned short* oz = (unsigned short*)WqT + (long)z * 65536;
    transp64(inz, oz, 256, 256, x * 64, y * 64, tid);
  } else {
    // ---- Wo transpose: 1024x256 ----
    int bb = b - 3264;
    int x = bb & 15, y = bb >> 4;
    transp64(Wo, (unsigned short*)WoT, 1024, 256, x * 64, y * 64, tid);
  }
}

// ---------------------------------------------------------------------------
// Merged Q+K GEMM: one 4096-block launch; id<2048 computes Q, else K.
// ---------------------------------------------------------------------------
__global__ __launch_bounds__(256) void gemm_qk(
    const short* __restrict__ Aq, const short* __restrict__ Btq,
    const float* __restrict__ biasq, short* __restrict__ Cq,
    const short* __restrict__ Ak, const short* __restrict__ Btk,
    const float* __restrict__ biask, short* __restrict__ Ck,
    float qscale)
{
  int idg = blockIdx.x;
  int sel = idg >> 11;               // 0 = Q, 1 = K
  int id = idg & 2047;
  const short* A  = sel ? Ak : Aq;
  const short* Bt = sel ? Btk : Btq;
  const float* bias = sel ? biask : biasq;
  short* Co = sel ? Ck : Cq;
  float scale = sel ? 1.0f : qscale;

  int y = id & 3, h = (id >> 2) & 3;
  int g = id >> 4;
  int xt = g & 31, bsel = g >> 5;
  int z = bsel * 4 + h;

  const short* Az = A + (long)bsel * 1048576;
  const short* Btz = Bt + (long)h * 65536;
  const float* biasz = bias + (long)h * 256;
  short* Cz = Co + (long)z * 1048576;

  int tid = threadIdx.x;
  int w = tid >> 6, lane = tid & 63;
  int half = lane >> 5, ln = lane & 31;
  int wm = w & 1, wn = w >> 1;
  int row0 = xt * 128 + wm * 64;
  int col0 = y * 64 + wn * 32;

  f16v acc0, acc1;
#pragma unroll
  for (int i = 0; i < 16; ++i) { acc0[i] = 0.f; acc1[i] = 0.f; }

  const short* ap0 = Az + (long)(row0 + ln) * 256 + half * 8;
  const short* ap1 = Az + (long)(row0 + 32 + ln) * 256 + half * 8;
  const short* bp  = Btz + (long)(col0 + ln) * 256 + half * 8;

#pragma unroll
  for (int kt = 0; kt < 16; ++kt) {
    bfrag a0 = *(const bfrag*)(ap0 + kt * 16);
    bfrag a1 = *(const bfrag*)(ap1 + kt * 16);
    bfrag bbv = *(const bfrag*)(bp + kt * 16);
    acc0 = __builtin_amdgcn_mfma_f32_32x32x16_bf16(a0, bbv, acc0, 0, 0, 0);
    acc1 = __builtin_amdgcn_mfma_f32_32x32x16_bf16(a1, bbv, acc1, 0, 0, 0);
  }

  int col = col0 + ln;
  float bv = biasz[col];
#pragma unroll
  for (int t = 0; t < 2; ++t) {
    int rbase = row0 + t * 32;
#pragma unroll
    for (int r = 0; r < 16; ++r) {
      float av = t ? acc1[r] : acc0[r];
      int rr = rbase + (r & 3) + 8 * (r >> 2) + 4 * half;
      ((unsigned short*)Cz)[(long)rr * 256 + col] = f2bf((av + bv) * scale);
    }
  }
}

// ---------------------------------------------------------------------------
// V GEMM (transC): V^T = ((img+pos) @ WvT + bv)^T. Separate launch (its
// output region overlaps peT/imgT — stream order is load-bearing).
// ---------------------------------------------------------------------------
__global__ __launch_bounds__(256) void gemm_v(
    const short* __restrict__ A, const short* __restrict__ Bt,
    const float* __restrict__ bias, short* __restrict__ Co)
{
  int id = blockIdx.x;
  int y = id & 3, h = (id >> 2) & 3;
  int g = id >> 4;
  int xt = g & 31, bsel = g >> 5;
  int z = bsel * 4 + h;

  const short* Az = A + (long)bsel * 1048576;
  const short* Btz = Bt + (long)h * 65536;
  const float* biasz = bias + (long)h * 256;
  short* Cz = Co + (long)z * 1048576;

  int tid = threadIdx.x;
  int w = tid >> 6, lane = tid & 63;
  int half = lane >> 5, ln = lane & 31;
  int wm = w & 1, wn = w >> 1;
  int row0 = xt * 128 + wm * 64;
  int col0 = y * 64 + wn * 32;

  f16v acc0, acc1;
#pragma unroll
  for (int i = 0; i < 16; ++i) { acc0[i] = 0.f; acc1[i] = 0.f; }

  const short* ap0 = Az + (long)(row0 + ln) * 256 + half * 8;
  const short* ap1 = Az + (long)(row0 + 32 + ln) * 256 + half * 8;
  const short* bp  = Btz + (long)(col0 + ln) * 256 + half * 8;

#pragma unroll
  for (int kt = 0; kt < 16; ++kt) {
    bfrag a0 = *(const bfrag*)(ap0 + kt * 16);
    bfrag a1 = *(const bfrag*)(ap1 + kt * 16);
    bfrag bbv = *(const bfrag*)(bp + kt * 16);
    acc0 = __builtin_amdgcn_mfma_f32_32x32x16_bf16(a0, bbv, acc0, 0, 0, 0);
    acc1 = __builtin_amdgcn_mfma_f32_32x32x16_bf16(a1, bbv, acc1, 0, 0, 0);
  }

  int col = col0 + ln;
  float bv = biasz[col];
#pragma unroll
  for (int t = 0; t < 2; ++t) {
    int rbase = row0 + t * 32;
#pragma unroll
    for (int g2 = 0; g2 < 4; ++g2) {
      float v0 = (t ? acc1[4*g2+0] : acc0[4*g2+0]) + bv;
      float v1 = (t ? acc1[4*g2+1] : acc0[4*g2+1]) + bv;
      float v2 = (t ? acc1[4*g2+2] : acc0[4*g2+2]) + bv;
      float v3 = (t ? acc1[4*g2+3] : acc0[4*g2+3]) + bv;
      uint2 st;
      st.x = pkbf(v0, v1);
      st.y = pkbf(v2, v3);
      *(uint2*)&((unsigned short*)Cz)[(long)col * 4096 + rbase + 8 * g2 + 4 * half] = st;
    }
  }
}

// ---------------------------------------------------------------------------
// Output projection (compile-time shape M=16384 N=256 K=1024), r8 form.
// ---------------------------------------------------------------------------
__global__ __launch_bounds__(256) void gemm_out(
    const short* __restrict__ A, const short* __restrict__ Bt,
    const float* __restrict__ bias, float* __restrict__ Co,
    const float* __restrict__ resid)
{
  int id = blockIdx.x;
  int xt = id >> 2, y = id & 3;

  int tid = threadIdx.x;
  int w = tid >> 6, lane = tid & 63;
  int half = lane >> 5, ln = lane & 31;
  int wm = w & 1, wn = w >> 1;
  int row0 = xt * 128 + wm * 64;
  int col0 = y * 64 + wn * 32;

  f16v acc0, acc1;
#pragma unroll
  for (int i = 0; i < 16; ++i) { acc0[i] = 0.f; acc1[i] = 0.f; }

  int r0 = row0 + ln, r1 = row0 + 32 + ln;
  long a0base = (long)(r0 >> 12) * 4194304 + (long)(r0 & 4095) * 256 + half * 8;
  long a1base = (long)(r1 >> 12) * 4194304 + (long)(r1 & 4095) * 256 + half * 8;
  const short* bp = Bt + (long)(col0 + ln) * 1024 + half * 8;

  for (int kh = 0; kh < 4; ++kh) {          // head-major K blocks
    const short* a0p = A + a0base + (long)kh * 1048576;
    const short* a1p = A + a1base + (long)kh * 1048576;
    const short* bkp = bp + kh * 256;
#pragma unroll
    for (int kt = 0; kt < 16; ++kt) {
      bfrag a0 = *(const bfrag*)(a0p + kt * 16);
      bfrag a1 = *(const bfrag*)(a1p + kt * 16);
      bfrag bbv = *(const bfrag*)(bkp + kt * 16);
      acc0 = __builtin_amdgcn_mfma_f32_32x32x16_bf16(a0, bbv, acc0, 0, 0, 0);
      acc1 = __builtin_amdgcn_mfma_f32_32x32x16_bf16(a1, bbv, acc1, 0, 0, 0);
    }
  }

  int col = col0 + ln;
  float bv = bias[col];
#pragma unroll
  for (int t = 0; t < 2; ++t) {
    int rbase = row0 + t * 32;
#pragma unroll
    for (int r = 0; r < 16; ++r) {
      float av = t ? acc1[r] : acc0[r];
      int rr = rbase + (r & 3) + 8 * (r >> 2) + 4 * half;
      Co[(long)rr * 256 + col] = av + bv + resid[(long)rr * 256 + col];
    }
  }
}

// ---------------------------------------------------------------------------
// Flash attention — EXACT ROUND-9 KERNEL (264.4 µs, best measured).
// softmax-early 2-deep S pipeline: iter t runs [S-MFMA(t)] || [softmax(t-1)
// on VALU] -> O-MFMAs(t-1). qf[8..15] live in per-wave LDS; SA/SB static
// rotation. K+V DMA-staged with pre-swizzled global source.
// Closed: setprio (r1), 4-wave 2-block/CU (r3/r5), launch-fusion (r6-null),
// K-direct-from-global (r10: vmcnt aliases with V-DMA + VMEM latency on the
// serial S-chain at 2 waves/SIMD -> 3.3x regression. Never mix global MFMA
// operands with global_load_lds staging.)
// ---------------------------------------------------------------------------
__global__ __launch_bounds__(512, 2) void attn_kernel(
    const short* __restrict__ Qg, const short* __restrict__ Kg,
    const short* __restrict__ Vtg, short* __restrict__ attc)
{
  __shared__ char smem[131072];  // [0,64K): K/V dbuf; [64K,128K): Q frags 8..15
  int bx = blockIdx.x;
  int bh = bx & 15, qg = bx >> 4;          // head-major XCD swizzle (load-bearing)
  int tid = threadIdx.x;
  int w = tid >> 6, lane = tid & 63;
  int half = lane >> 5, ln = lane & 31;
  int q0 = qg * 256 + w * 32;

  // Q fragments: kt 0..7 in registers; kt 8..15 in per-wave LDS (write-once,
  // read-own-region only -> no barrier needed beyond in-wave lgkmcnt order).
  bfrag qf[8];
  int qoff = 65536 + w * 8192 + lane * 16;
  {
    const short* qrow = Qg + ((long)bh * 4096 + q0 + ln) * 256 + half * 8;
#pragma unroll
    for (int kt = 0; kt < 8; ++kt) qf[kt] = *(const bfrag*)(qrow + kt * 16);
#pragma unroll
    for (int kt = 8; kt < 16; ++kt) {
      us8 v = *(const us8*)(qrow + kt * 16);
      *(us8*)(smem + qoff + (kt - 8) * 1024) = v;
    }
  }

  // MFMA-read LDS byte offsets
  int koff[4], voff[2];
#pragma unroll
  for (int m = 0; m < 4; ++m) koff[m] = ((ln ^ (2 * m + half)) * 16) + half * 512;
#pragma unroll
  for (int kp = 0; kp < 2; ++kp) {
    int ck = 2 * kp + half;
    voff[kp] = 16384 + ck * 4096 + ((ln ^ (ck << 1)) * 16);
  }

  // DMA source offsets (inverse swizzle on the global side), as r4-r9.
  int w2 = w * 2;
  int kgl0, kgl1, vgl0, vgl1;
  {
    int c0 = w2 * 2 + half;
    kgl0 = (ln ^ (c0 & 7)) * 512 + c0 * 16;
    int c1 = (w2 + 1) * 2 + half;
    kgl1 = (ln ^ (c1 & 7)) * 512 + c1 * 16;
    int ck0 = w2 >> 2;
    int e0 = ((w2 & 3) * 64 + lane) ^ (ck0 << 1);
    vgl0 = e0 * 8192 + ck0 * 16;
    int ck1 = (w2 + 1) >> 2;
    int e1 = (((w2 + 1) & 3) * 64 + lane) ^ (ck1 << 1);
    vgl1 = e1 * 8192 + ck1 * 16;
  }
  const char* kgp = (const char*)Kg + (long)bh * 2097152;   // += 16384 per tile
  const char* vgp = (const char*)Vtg + (long)bh * 2097152;  // += 64 per tile

  f16v O[8];
#pragma unroll
  for (int t = 0; t < 8; ++t)
#pragma unroll
    for (int r = 0; r < 16; ++r) O[t][r] = 0.f;

  float l_run = 0.f;
  union { bfrag f; unsigned u[4]; } bb[2];
  f16v SA, SB;                      // two-deep S pipeline (static rotation)

// softmax P-pack from SV: cvt_pk pairs + permlane32_swap lane-halves exchange.
#define PACK_BB(kp, SV)                                                        \
  {                                                                            \
    unsigned q0_, q1_, q2_, q3_;                                               \
    asm("v_cvt_pk_bf16_f32 %0, %1, %2"                                         \
        : "=v"(q0_) : "v"(SV[8*(kp)+0]), "v"(SV[8*(kp)+1]));                   \
    asm("v_cvt_pk_bf16_f32 %0, %1, %2"                                         \
        : "=v"(q1_) : "v"(SV[8*(kp)+2]), "v"(SV[8*(kp)+3]));                   \
    asm("v_cvt_pk_bf16_f32 %0, %1, %2"                                         \
        : "=v"(q2_) : "v"(SV[8*(kp)+4]), "v"(SV[8*(kp)+5]));                   \
    asm("v_cvt_pk_bf16_f32 %0, %1, %2"                                         \
        : "=v"(q3_) : "v"(SV[8*(kp)+6]), "v"(SV[8*(kp)+7]));                   \
    asm("v_permlane32_swap_b32 %0, %1" : "+v"(q0_), "+v"(q2_));                \
    asm("v_permlane32_swap_b32 %0, %1" : "+v"(q1_), "+v"(q3_));                \
    bb[kp].u[0] = q0_;                                                         \
    bb[kp].u[1] = q1_;                                                         \
    bb[kp].u[2] = q2_;                                                         \
    bb[kp].u[3] = q3_;                                                         \
  }

// exp/sum/pack of SV (tile t-1) -> l_run, bb
#define SOFTMAX_BB(SV)                                                         \
  {                                                                            \
    float ss = 0.f;                                                            \
    _Pragma("unroll")                                                          \
    for (int r = 0; r < 16; ++r) { float e = exp2f(SV[r] - 8.f); SV[r] = e; ss += e; } \
    l_run += ss;                                                               \
    PACK_BB(0, SV)                                                             \
    PACK_BB(1, SV)                                                             \
  }

// S-MFMA chain for the current tile from buf BUF into SNEW
#define SCHAIN(BUF, SNEW)                                                      \
  {                                                                            \
    _Pragma("unroll")                                                          \
    for (int r = 0; r < 16; ++r) SNEW[r] = 0.f;                                \
    _Pragma("unroll")                                                          \
    for (int kt = 0; kt < 8; ++kt) {                                           \
      bfrag a = *(const bfrag*)(smem + koff[kt & 3] + ((BUF)*32768 + kt*1024));\
      SNEW = __builtin_amdgcn_mfma_f32_32x32x16_bf16(a, qf[kt], SNEW, 0, 0, 0);\
    }                                                                          \
    _Pragma("unroll")                                                          \
    for (int kt = 8; kt < 16; ++kt) {                                          \
      bfrag a = *(const bfrag*)(smem + koff[kt & 3] + ((BUF)*32768 + kt*1024));\
      bfrag qv = *(const bfrag*)(smem + qoff + (kt - 8) * 1024);               \
      SNEW = __builtin_amdgcn_mfma_f32_32x32x16_bf16(a, qv, SNEW, 0, 0, 0);    \
    }                                                                          \
  }

  // prologue: DMA K_0 into buf0
  dma16(kgp + kgl0, smem + w2 * 1024);
  dma16(kgp + kgl1, smem + (w2 + 1) * 1024);
  kgp += 16384;

  // iter 0: S(K_0) -> SB; DMA K_1 + V_0 into buf1. No softmax, no O yet.
  __syncthreads();
  dma16(kgp + kgl0, smem + 32768 + w2 * 1024);
  dma16(kgp + kgl1, smem + 32768 + (w2 + 1) * 1024);
  kgp += 16384;
  dma16(vgp + vgl0, smem + 32768 + 16384 + w2 * 1024);
  dma16(vgp + vgl1, smem + 32768 + 16384 + (w2 + 1) * 1024);
  vgp += 64;
  SCHAIN(0, SB)

// iteration t: reads K_t + V_{t-1} from buf BUF; DMAs K_{t+1}+V_t to BUF^1.
// S(t) -> SNEW while softmax(t-1) on SPREV runs on VALU; then O += V_{t-1}*bb.
#define ATTN_ITER(BUF, KLOAD, SNEW, SPREV)                                     \
  {                                                                            \
    __syncthreads();                                                           \
    if (KLOAD) {                                                               \
      dma16(kgp + kgl0, smem + ((BUF) ^ 1) * 32768 + w2 * 1024);               \
      dma16(kgp + kgl1, smem + ((BUF) ^ 1) * 32768 + (w2 + 1) * 1024);         \
      kgp += 16384;                                                            \
    }                                                                          \
    dma16(vgp + vgl0, smem + ((BUF) ^ 1) * 32768 + 16384 + w2 * 1024);         \
    dma16(vgp + vgl1, smem + ((BUF) ^ 1) * 32768 + 16384 + (w2 + 1) * 1024);   \
    vgp += 64;                                                                 \
    SCHAIN(BUF, SNEW)                                                          \
    SOFTMAX_BB(SPREV)                                                          \
    _Pragma("unroll")                                                          \
    for (int kt = 0; kt < 16; ++kt) {                                          \
      bfrag va = *(const bfrag*)(smem + voff[kt >> 3] +                        \
                                 ((BUF)*32768 + (kt & 7) * 512));              \
      O[kt & 7] = __builtin_amdgcn_mfma_f32_32x32x16_bf16(va, bb[kt >> 3].f,   \
                                                          O[kt & 7], 0, 0, 0); \
    }                                                                          \
  }

  // t = 1..126 as 63 static-parity pairs, then t = 127.
  for (int tp = 0; tp < 63; ++tp) {
    ATTN_ITER(1, 1, SA, SB)     // odd t: new S in SA, softmax SB
    ATTN_ITER(0, 1, SB, SA)     // even t
  }
  ATTN_ITER(1, 0, SA, SB)       // t = 127: no K prefetch; V_127 -> buf0

  // epilogue: softmax(S_127)=SA, then V-MFMA for tile 127 (buf0 V half)
  __syncthreads();
  SOFTMAX_BB(SA)
#pragma unroll
  for (int kp = 0; kp < 2; ++kp) {
#pragma unroll
    for (int mt = 0; mt < 8; ++mt) {
      bfrag va = *(const bfrag*)(smem + voff[kp] + mt * 512);
      O[mt] = __builtin_amdgcn_mfma_f32_32x32x16_bf16(va, bb[kp].f, O[mt], 0, 0, 0);
    }
  }
#undef ATTN_ITER
#undef SCHAIN
#undef SOFTMAX_BB
#undef PACK_BB

  // attc[bh][q][e] = O^T[e][q]/l.  l = own-half + partner-half.
  l_run += __shfl_xor(l_run, 32);
  float rl = 1.0f / l_run;
  short* orow = attc + ((long)bh * 4096 + q0 + ln) * 256;
#pragma unroll
  for (int mt = 0; mt < 8; ++mt) {
#pragma unroll
    for (int g = 0; g < 4; ++g) {
      uint2 st;
      st.x = pkbf(O[mt][4 * g + 0] * rl, O[mt][4 * g + 1] * rl);
      st.y = pkbf(O[mt][4 * g + 2] * rl, O[mt][4 * g + 3] * rl);
      *(uint2*)(orow + mt * 32 + 8 * g + 4 * half) = st;
    }
  }
}

// ---------------------------------------------------------------------------
// FFN head (all fp32): 16 rows per 256-thr block, 4 rows per wave.
// ---------------------------------------------------------------------------
__global__ __launch_bounds__(256) void ffn_kernel(
    const float* __restrict__ emb,
    const float* __restrict__ W1, const float* __restrict__ b1,
    const float* __restrict__ g1, const float* __restrict__ be1,
    const float* __restrict__ W2, const float* __restrict__ b2,
    const float* __restrict__ g2, const float* __restrict__ be2,
    const float* __restrict__ W3, const float* __restrict__ b3,
    float* __restrict__ act)
{
  __shared__ float xs[4][256][4];   // [wave][k][row]  16KB
  __shared__ float hs[4][128][4];   // [wave][k][row]   8KB
  int w = threadIdx.x >> 6, l = threadIdx.x & 63;
  int row0 = blockIdx.x * 16 + w * 4;
  const float* x = emb + (long)row0 * 256;

  {
    float xv[4][4];
#pragma unroll
    for (int rr = 0; rr < 4; ++rr) {
      float4 t = *(const float4*)(x + rr * 256 + 4 * l);
      xv[0][rr] = t.x; xv[1][rr] = t.y; xv[2][rr] = t.z; xv[3][rr] = t.w;
    }
#pragma unroll
    for (int i = 0; i < 4; ++i) {
      float4 st = make_float4(xv[i][0], xv[i][1], xv[i][2], xv[i][3]);
      *(float4*)&xs[w][4 * l + i][0] = st;
    }
  }

  float a0[4], a1[4];
  {
    float bb0 = b1[2 * l], bb1 = b1[2 * l + 1];
#pragma unroll
    for (int rr = 0; rr < 4; ++rr) { a0[rr] = bb0; a1[rr] = bb1; }
  }
  for (int k = 0; k < 256; ++k) {
    float w0 = W1[k * 128 + 2 * l], w1 = W1[k * 128 + 2 * l + 1];
    float4 xv = *(const float4*)&xs[w][k][0];
    a0[0] += xv.x * w0; a1[0] += xv.x * w1;
    a0[1] += xv.y * w0; a1[1] += xv.y * w1;
    a0[2] += xv.z * w0; a1[2] += xv.z * w1;
    a0[3] += xv.w * w0; a1[3] += xv.w * w1;
  }
  {
    float gg0 = g1[2 * l], gg1 = g1[2 * l + 1];
    float ee0 = be1[2 * l], ee1 = be1[2 * l + 1];
    float n0v[4], n1v[4];
#pragma unroll
    for (int rr = 0; rr < 4; ++rr) {
      float u0 = fmaxf(a0[rr], 0.f), u1 = fmaxf(a1[rr], 0.f);
      float s1 = wred(u0 + u1);
      float s2 = wred(u0 * u0 + u1 * u1);
      float mu = s1 * (1.f / 128.f);
      float var = fmaxf(s2 * (1.f / 128.f) - mu * mu, 0.f);
      float rs = rsqrtf(var + 1e-5f);
      n0v[rr] = (u0 - mu) * rs * gg0 + ee0;
      n1v[rr] = (u1 - mu) * rs * gg1 + ee1;
    }
    *(float4*)&hs[w][2 * l][0]     = make_float4(n0v[0], n0v[1], n0v[2], n0v[3]);
    *(float4*)&hs[w][2 * l + 1][0] = make_float4(n1v[0], n1v[1], n1v[2], n1v[3]);
  }

  float c0[4];
  {
    float bb2 = b2[l];
#pragma unroll
    for (int rr = 0; rr < 4; ++rr) c0[rr] = bb2;
  }
  for (int k = 0; k < 128; ++k) {
    float w2 = W2[k * 64 + l];
    float4 hv = *(const float4*)&hs[w][k][0];
    c0[0] += hv.x * w2;
    c0[1] += hv.y * w2;
    c0[2] += hv.z * w2;
    c0[3] += hv.w * w2;
  }
  {
    float gg2 = g2[l], ee2 = be2[l], w3 = W3[l], bb3 = b3[0];
#pragma unroll
    for (int rr = 0; rr < 4; ++rr) {
      float u = fmaxf(c0[rr], 0.f);
      float t1 = wred(u);
      float t2 = wred(u * u);
      float mu2 = t1 * (1.f / 64.f);
      float var2 = fmaxf(t2 * (1.f / 64.f) - mu2 * mu2, 0.f);
      float rs2 = rsqrtf(var2 + 1e-5f);
      float n2 = (u - mu2) * rs2 * gg2 + ee2;
      float tt = wred(n2 * w3);
      if (l == 0) {
        float r = tt + bb3;
        act[row0 + rr] = 1.f / (1.f + __expf(-r));
      }
    }
  }
}

// ---------------------------------------------------------------------------
extern "C" void kernel_launch(void* const* d_in, const int* in_sizes, int n_in,
                              void* d_out, int out_size, void* d_ws, size_t ws_size,
                              hipStream_t stream)
{
  const float* img_emb   = (const float*)d_in[0];
  const float* point_emb = (const float*)d_in[1];
  const float* Wq = (const float*)d_in[2];
  const float* bq = (const float*)d_in[3];
  const float* Wk = (const float*)d_in[4];
  const float* bk = (const float*)d_in[5];
  const float* Wv = (const float*)d_in[6];
  const float* bv = (const float*)d_in[7];
  const float* Wo = (const float*)d_in[8];
  const float* bo = (const float*)d_in[9];
  const float* pos = (const float*)d_in[10];
  const float* W1 = (const float*)d_in[11];
  const float* b1 = (const float*)d_in[12];
  const float* g1 = (const float*)d_in[13];
  const float* be1 = (const float*)d_in[14];
  const float* W2 = (const float*)d_in[15];
  const float* b2 = (const float*)d_in[16];
  const float* g2 = (const float*)d_in[17];
  const float* be2 = (const float*)d_in[18];
  const float* W3 = (const float*)d_in[19];
  const float* b3 = (const float*)d_in[20];

  // ws layout (111.1 MB), all internal tensors bf16.
  // peT/imgT live INSIDE the VtB region: both are dead before gemm_v (the
  // only writer of VtB) runs — stream order guarantees safety.
  char* ws = (char*)d_ws;
  short* Qb      = (short*)(ws + 0);            // 33.55 MB [BH][4096][256]; attn out in-place
  short* Kb      = (short*)(ws + 33554432);     // 33.55 MB [BH][4096][256]
  short* VtB     = (short*)(ws + 67108864);     // 33.55 MB [BH][256][4096]
  short* peT     = (short*)(ws + 67108864);     //  8.39 MB (dead after QK launch)
  short* imgT    = (short*)(ws + 75497472);     //  8.39 MB (dead after QK launch)
  short* imgPosT = (short*)(ws + 100663296);    //  8.39 MB
  short* WoT     = (short*)(ws + 109051904);    //  0.52 MB [256][1024]
  short* WqT     = (short*)(ws + 109576192);    //  0.13 MB [H][256][256]  (WkT,WvT follow)
  short* WkT     = (short*)(ws + 110100480);
  short* WvT     = (short*)(ws + 110624768);
  (void)WkT; (void)WvT;

  float* act_out = (float*)d_out;            // [B*N]
  float* emb_out = (float*)d_out + 16384;    // [B*N][256]

  const float qscale = 0.0901684400555602f;  // log2(e)/sqrt(256)

  // fused prep: all weight transposes + img transpose/pos-add + point_emb cast
  prep_kernel<<<3328, 256, 0, stream>>>(point_emb, peT, img_emb, pos,
                                        imgT, imgPosT, Wq, Wk, Wv, WqT, Wo, WoT);

  // Q and K GEMMs merged into one launch (no aliasing between their buffers)
  gemm_qk<<<4096, 256, 0, stream>>>(peT, WqT, bq, Qb,
                                    imgT, WqT + 262144, bk, Kb, qscale);
  // V^T = ((img + pos) @ WvT + bv)^T   (writes VtB over peT/imgT — after QK)
  gemm_v<<<2048, 256, 0, stream>>>(imgPosT, WqT + 524288, bv, VtB);

  // attention: reads Qb/Kb/VtB, writes att in-place over Qb ([BH][N][256])
  attn_kernel<<<256, 512, 0, stream>>>(Qb, Kb, VtB, Qb);

  // emb = att @ Wo + bo + point_emb  (fp32 out)
  gemm_out<<<512, 256, 0, stream>>>(Qb, WoT, bo, emb_out, point_emb);

  // FFN head -> act (fp32)
  ffn_kernel<<<1024, 256, 0, stream>>>(emb_out, W1, b1, g1, be1, W2, b2, g2, be2,
                                       W3, b3, act_out);
}